// Round 2
// baseline (5416.929 us; speedup 1.0000x reference)
//
#include <hip/hip_runtime.h>
#include <stdint.h>

typedef unsigned short u16;
typedef unsigned int u32;

#define NB 64      // batches per block
#define NWAVE 16   // waves per block
#define HISTN 64
#define TGEN 193   // L+1

// strides (elements)
#define S_NOISE 2048   // 256*8
#define S_HIST  192    // 64*3
#define S_GAP   386    // 193*2
#define S_OUT   771    // 257*3

// LDS layout (floats)
#define OFF_WHH 0                    // [j][g][k] 64*4*64 = 16384
#define OFF_WIH (OFF_WHH + 16384)    // [j][g][k16] 64*4*16 = 4096
#define OFF_W1  (OFF_WIH + 4096)     // [j][k] 64*64 = 4096
#define OFF_H   (OFF_W1 + 4096)      // [k][b] 64*64 = 4096
#define OFF_ZP  (OFF_H + 4096)       // [w][b] 16*64 = 1024
#define OFF_BIAS (OFF_ZP + 1024)     // [j*4+g] 256
#define OFF_B1  (OFF_BIAS + 256)     // 64
#define OFF_W2  (OFF_B1 + 64)        // 64
#define OFF_B2  (OFF_W2 + 64)        // 64 (pad)
#define LDS_FLOATS (OFF_B2 + 64)

__device__ __forceinline__ float b2f(u16 u) {
    return __uint_as_float(((u32)u) << 16);
}
__device__ __forceinline__ u16 f2b(float f) {
    u32 u = __float_as_uint(f);
    u32 r = (u + 0x7fffu + ((u >> 16) & 1u)) >> 16;
    return (u16)r;
}
__device__ __forceinline__ float sigf(float x) {
    return 1.0f / (1.0f + __expf(-x));
}
__device__ __forceinline__ float tanhf_(float x) {
    x = fminf(fmaxf(x, -30.0f), 30.0f);
    float e = __expf(2.0f * x);
    return (e - 1.0f) / (e + 1.0f);
}
// generic element load: idx-th element of array p under detected dtype
__device__ __forceinline__ float ldv(const void* p, int idx, bool f32) {
    return f32 ? ((const float*)p)[idx] : b2f(((const u16*)p)[idx]);
}

// One LSTM cell step. Lane = batch. Wave w owns units 4w..4w+3.
__device__ __forceinline__ void lstm_step(
    const float* whh, const float* wih, const float* bias, float* hb,
    int lane, int w, float (&c)[4], const float (&x)[12])
{
    float acc[4][4];
#pragma unroll
    for (int jj = 0; jj < 4; jj++) {
        int j = (w << 2) | jj;
#pragma unroll
        for (int g = 0; g < 4; g++) acc[jj][g] = bias[(j << 2) | g];
    }
#pragma unroll
    for (int jj = 0; jj < 4; jj++) {
        int j = (w << 2) | jj;
#pragma unroll
        for (int g = 0; g < 4; g++) {
            const float4* wr = reinterpret_cast<const float4*>(&wih[((j << 2) | g) << 4]);
            float a = acc[jj][g];
#pragma unroll
            for (int q = 0; q < 3; q++) {
                float4 wv = wr[q];
                a += wv.x * x[q * 4 + 0] + wv.y * x[q * 4 + 1] +
                     wv.z * x[q * 4 + 2] + wv.w * x[q * 4 + 3];
            }
            acc[jj][g] = a;
        }
    }
#pragma unroll 1
    for (int kc = 0; kc < 4; kc++) {
        float hr[16];
#pragma unroll
        for (int i = 0; i < 16; i++) hr[i] = hb[(((kc << 4) | i) << 6) | lane];
#pragma unroll
        for (int jj = 0; jj < 4; jj++) {
            int j = (w << 2) | jj;
#pragma unroll
            for (int g = 0; g < 4; g++) {
                const float4* wr = reinterpret_cast<const float4*>(
                    &whh[(((j << 2) | g) << 6) + (kc << 4)]);
                float a = acc[jj][g];
#pragma unroll
                for (int q = 0; q < 4; q++) {
                    float4 wv = wr[q];
                    a += wv.x * hr[q * 4 + 0] + wv.y * hr[q * 4 + 1] +
                         wv.z * hr[q * 4 + 2] + wv.w * hr[q * 4 + 3];
                }
                acc[jj][g] = a;
            }
        }
    }
    float hn[4];
#pragma unroll
    for (int jj = 0; jj < 4; jj++) {
        float iv = sigf(acc[jj][0]);
        float fv = sigf(acc[jj][1]);
        float gv = tanhf_(acc[jj][2]);
        float ov = sigf(acc[jj][3]);
        float cc = fv * c[jj] + iv * gv;
        c[jj] = cc;
        hn[jj] = ov * tanhf_(cc);
    }
    __syncthreads();  // everyone done reading h_{t-1}
#pragma unroll
    for (int jj = 0; jj < 4; jj++) hb[((((w << 2) | jj)) << 6) | lane] = hn[jj];
    __syncthreads();  // h_t visible
}

extern "C" __global__ void __launch_bounds__(1024)
lstm_gen_kernel(const void* __restrict__ noise, const void* __restrict__ hist_x,
                const void* __restrict__ gap, const void* __restrict__ pW_ih,
                const void* __restrict__ pW_hh, const void* __restrict__ pb_ih,
                const void* __restrict__ pb_hh, const void* __restrict__ pW1,
                const void* __restrict__ pb1, const void* __restrict__ pW2,
                const void* __restrict__ pb2, void* __restrict__ out)
{
    extern __shared__ float lds[];
    float* whh = lds + OFF_WHH;
    float* wih = lds + OFF_WIH;
    float* w1l = lds + OFF_W1;
    float* hb  = lds + OFF_H;
    float* zpl = lds + OFF_ZP;
    float* bias = lds + OFF_BIAS;
    float* b1l = lds + OFF_B1;
    float* w2l = lds + OFF_W2;
    float* b2l = lds + OFF_B2;

    const int tid = threadIdx.x;
    const int lane = tid & 63;
    const int w = tid >> 6;
    const int batch = blockIdx.x * NB + lane;

    // ---- dtype detection (wave-uniform): bf16 reading of fp32 data explodes ----
    // Weights are uniform(-0.125, 0.125). If the buffer is bf16, every u16 half
    // decodes to |v| < 0.13. If it's fp32, the low halves are random mantissa
    // bits -> as bf16, P(|v| <= 0.5) ~ 0.5 per word, (~0.5)^64 overall miss.
    bool is_f32 = false;
    {
        const u32* p = (const u32*)pW_hh;
        for (int i = 0; i < 64; i++) {
            u32 v = p[i];
            float a = b2f((u16)(v & 0xffffu));
            float b = b2f((u16)(v >> 16));
            if (!(fabsf(a) <= 0.5f) || !(fabsf(b) <= 0.5f)) is_f32 = true;  // NaN counts
        }
    }

    // ---- stage weights into LDS (fp32 compute; exact for either input dtype) ----
    for (int i = tid; i < 16384; i += 1024) {
        int j = i >> 8, g = (i >> 6) & 3, k = i & 63;
        whh[i] = ldv(pW_hh, (((g << 6) | j) << 6) | k, is_f32);
    }
    for (int i = tid; i < 4096; i += 1024) {
        int j = i >> 6, g = (i >> 4) & 3, k = i & 15;
        wih[i] = (k < 12) ? ldv(pW_ih, ((g << 6) | j) * 12 + k, is_f32) : 0.0f;
    }
    for (int i = tid; i < 4096; i += 1024) w1l[i] = ldv(pW1, i, is_f32);
    for (int i = tid; i < 4096; i += 1024) hb[i] = 0.0f;
    if (tid < 256) {
        int j = tid >> 2, g = tid & 3;
        bias[tid] = ldv(pb_ih, (g << 6) | j, is_f32) + ldv(pb_hh, (g << 6) | j, is_f32);
    }
    if (tid < 64) { b1l[tid] = ldv(pb1, tid, is_f32); w2l[tid] = ldv(pW2, tid, is_f32); }
    if (tid == 0) b2l[0] = ldv(pb2, 0, is_f32);
    __syncthreads();

    float c[4] = {0.f, 0.f, 0.f, 0.f};
    float dist = 0.0f;

    const u16* nzp_h = (const u16*)noise + (size_t)batch * S_NOISE;
    const float* nzp_f = (const float*)noise + (size_t)batch * S_NOISE;
    const u16* hxp_h = (const u16*)hist_x + (size_t)batch * S_HIST;
    const float* hxp_f = (const float*)hist_x + (size_t)batch * S_HIST;
    const u16* gdp_h = (const u16*)gap + (size_t)batch * S_GAP;
    const float* gdp_f = (const float*)gap + (size_t)batch * S_GAP;
    u16* outp_h = (u16*)out + (size_t)batch * S_OUT;
    float* outp_f = (float*)out + (size_t)batch * S_OUT;

    // ---- conditioning phase: 64 steps ----
#pragma unroll 1
    for (int t = 0; t < HISTN; t++) {
        float x[12];
        if (is_f32) {
            x[0] = hxp_f[t * 3 + 0]; x[1] = hxp_f[t * 3 + 1]; x[2] = hxp_f[t * 3 + 2];
            const float4* q = reinterpret_cast<const float4*>(&nzp_f[t * 8]);
            float4 a = q[0], b = q[1];
            x[4] = a.x; x[5] = a.y; x[6] = a.z; x[7] = a.w;
            x[8] = b.x; x[9] = b.y; x[10] = b.z; x[11] = b.w;
            if (w == 0) {
                outp_f[t * 3 + 0] = x[0]; outp_f[t * 3 + 1] = x[1]; outp_f[t * 3 + 2] = x[2];
            }
        } else {
            u16 u0 = hxp_h[t * 3 + 0], u1 = hxp_h[t * 3 + 1], u2 = hxp_h[t * 3 + 2];
            x[0] = b2f(u0); x[1] = b2f(u1); x[2] = b2f(u2);
            const uint4 nv = *reinterpret_cast<const uint4*>(&nzp_h[t * 8]);
            x[4] = b2f((u16)(nv.x & 0xffffu)); x[5] = b2f((u16)(nv.x >> 16));
            x[6] = b2f((u16)(nv.y & 0xffffu)); x[7] = b2f((u16)(nv.y >> 16));
            x[8] = b2f((u16)(nv.z & 0xffffu)); x[9] = b2f((u16)(nv.z >> 16));
            x[10] = b2f((u16)(nv.w & 0xffffu)); x[11] = b2f((u16)(nv.w >> 16));
            if (w == 0) {
                outp_h[t * 3 + 0] = u0; outp_h[t * 3 + 1] = u1; outp_h[t * 3 + 2] = u2;
            }
        }
        dist += x[2];
        x[3] = dist;
        lstm_step(whh, wih, bias, hb, lane, w, c, x);
    }

    // ---- generation phase: 193 steps ----
#pragma unroll 1
    for (int tg = 0; tg < TGEN; tg++) {
        // MLP head on h_prev (in hb): z = tanh(tanh(h@W1^T + b1)@W2^T + b2)
        float macc[4];
#pragma unroll
        for (int jj = 0; jj < 4; jj++) macc[jj] = b1l[(w << 2) | jj];
#pragma unroll 1
        for (int kc = 0; kc < 4; kc++) {
            float hr[16];
#pragma unroll
            for (int i = 0; i < 16; i++) hr[i] = hb[(((kc << 4) | i) << 6) | lane];
#pragma unroll
            for (int jj = 0; jj < 4; jj++) {
                int j = (w << 2) | jj;
                const float4* wr = reinterpret_cast<const float4*>(&w1l[(j << 6) + (kc << 4)]);
                float a = macc[jj];
#pragma unroll
                for (int q = 0; q < 4; q++) {
                    float4 wv = wr[q];
                    a += wv.x * hr[q * 4 + 0] + wv.y * hr[q * 4 + 1] +
                         wv.z * hr[q * 4 + 2] + wv.w * hr[q * 4 + 3];
                }
                macc[jj] = a;
            }
        }
        float zpsum = 0.0f;
#pragma unroll
        for (int jj = 0; jj < 4; jj++)
            zpsum += w2l[(w << 2) | jj] * tanhf_(macc[jj]);
        zpl[(w << 6) | lane] = zpsum;
        __syncthreads();
        float pre2 = b2l[0];
#pragma unroll
        for (int wi = 0; wi < NWAVE; wi++) pre2 += zpl[(wi << 6) | lane];
        float z = tanhf_(pre2);
        float dp = 24.0f * z;
        dist += dp;

        float x[12];
        if (is_f32) {
            x[0] = gdp_f[tg * 2 + 0]; x[1] = gdp_f[tg * 2 + 1];
        } else {
            u32 gdu = *reinterpret_cast<const u32*>(&gdp_h[tg * 2]);
            x[0] = b2f((u16)(gdu & 0xffffu)); x[1] = b2f((u16)(gdu >> 16));
        }
        x[2] = dp; x[3] = dist;
        if (tg < TGEN - 1) {
            if (is_f32) {
                const float4* q = reinterpret_cast<const float4*>(&nzp_f[(HISTN + tg) * 8]);
                float4 a = q[0], b = q[1];
                x[4] = a.x; x[5] = a.y; x[6] = a.z; x[7] = a.w;
                x[8] = b.x; x[9] = b.y; x[10] = b.z; x[11] = b.w;
            } else {
                const uint4 nv = *reinterpret_cast<const uint4*>(&nzp_h[(HISTN + tg) * 8]);
                x[4] = b2f((u16)(nv.x & 0xffffu)); x[5] = b2f((u16)(nv.x >> 16));
                x[6] = b2f((u16)(nv.y & 0xffffu)); x[7] = b2f((u16)(nv.y >> 16));
                x[8] = b2f((u16)(nv.z & 0xffffu)); x[9] = b2f((u16)(nv.z >> 16));
                x[10] = b2f((u16)(nv.w & 0xffffu)); x[11] = b2f((u16)(nv.w >> 16));
            }
        } else {
#pragma unroll
            for (int q = 4; q < 12; q++) x[q] = 0.0f;
        }
        if (w == 0) {
            if (is_f32) {
                outp_f[(HISTN + tg) * 3 + 0] = x[0];
                outp_f[(HISTN + tg) * 3 + 1] = x[1];
                outp_f[(HISTN + tg) * 3 + 2] = dp;
            } else {
                outp_h[(HISTN + tg) * 3 + 0] = f2b(x[0]);
                outp_h[(HISTN + tg) * 3 + 1] = f2b(x[1]);
                outp_h[(HISTN + tg) * 3 + 2] = f2b(dp);
            }
        }
        lstm_step(whh, wih, bias, hb, lane, w, c, x);
    }
}

extern "C" void kernel_launch(void* const* d_in, const int* in_sizes, int n_in,
                              void* d_out, int out_size, void* d_ws, size_t ws_size,
                              hipStream_t stream) {
    (void)in_sizes; (void)n_in; (void)d_ws; (void)ws_size; (void)out_size;
    const size_t smem = LDS_FLOATS * sizeof(float);  // ~118 KB
    hipFuncSetAttribute((const void*)lstm_gen_kernel,
                        hipFuncAttributeMaxDynamicSharedMemorySize, (int)smem);
    lstm_gen_kernel<<<128, 1024, smem, stream>>>(
        d_in[0], d_in[1], d_in[2], d_in[3], d_in[4], d_in[5],
        d_in[6], d_in[7], d_in[8], d_in[9], d_in[10], d_out);
}